// Round 7
// baseline (729.168 us; speedup 1.0000x reference)
//
#include <hip/hip_runtime.h>
#include <math.h>

// Problem constants: B=8, spatial 64x64 (HW=4096), C_mid=256, C=128, N=9 taps.
// All inputs/outputs are float32.
typedef const float* fp;

// ---------------- K0: dcn_w (o,c,9) -> Wt2[n][c][o] f32 (tap-major for per-tap combine)
__global__ __launch_bounds__(256) void k_wt2(fp dcn_w, float* Wt2){
    int i = blockIdx.x*256 + threadIdx.x;       // 147456
    int o = i & 127, c = (i >> 7) & 127, n = i >> 14;
    Wt2[i] = dcn_w[o*1152 + c*9 + n];
}

// ---------------- K1: bilinear up2x(align_corners) of x1 + concat with x2 -> A (8,256,64,64)
__global__ __launch_bounds__(256) void k_concat_up(fp x1, fp x2, float* A){
    int idx = blockIdx.x*256 + threadIdx.x;     // 8,388,608
    int x = idx & 63, y = (idx>>6)&63, c = (idx>>12)&255, b = idx>>20;
    float val;
    if (c < 128){
        val = x2[((b*128+c)<<12) + (y<<6) + x];
    } else {
        int cc = c - 128;
        const float s = 31.0f/63.0f;
        float fy = y*s, fx = x*s;
        int iy = (int)fy; if (iy > 30) iy = 30;
        int ix = (int)fx; if (ix > 30) ix = 30;
        float ty = fy - (float)iy, tx = fx - (float)ix;
        fp src = x1 + ((b*128+cc)<<10);
        float v00 = src[iy*32+ix],     v01 = src[iy*32+ix+1];
        float v10 = src[(iy+1)*32+ix], v11 = src[(iy+1)*32+ix+1];
        val = (v00*(1.f-ty)+v10*ty)*(1.f-tx) + (v01*(1.f-ty)+v11*ty)*tx;
    }
    A[idx] = val;
}

// ---------------- K2: depthwise 3x3 SAME over 256 ch + bias -> Bo
__global__ __launch_bounds__(256) void k_dw256(const float* A, fp w, fp bias, float* Bo){
    int idx = blockIdx.x*256 + threadIdx.x;     // 8,388,608
    int x = idx&63, y=(idx>>6)&63, c=(idx>>12)&255, b=idx>>20;
    const float* src = A + ((b*256+c)<<12);
    float acc = bias[c];
    #pragma unroll
    for(int ky=0; ky<3; ky++){
        int yy = y+ky-1; if(yy<0||yy>63) continue;
        #pragma unroll
        for(int kx=0; kx<3; kx++){
            int xx = x+kx-1; if(xx<0||xx>63) continue;
            acc += src[(yy<<6)+xx]*w[c*9+ky*3+kx];
        }
    }
    Bo[idx] = acc;
}

// ---------------- K3: pointwise 256->128 + bias -> Ccl (channel-last only)
__global__ __launch_bounds__(256) void k_pw(const float* Bi, fp w, fp bias, float* Ccl){
    __shared__ float sIn[256*32];
    int bid = blockIdx.x;                       // 1024
    int b = bid >> 7;
    int pix0 = (bid & 127) << 5;
    int tid = threadIdx.x;
    for(int j = tid; j < 256*32; j += 256){
        int c = j >> 5, p = j & 31;
        sIn[j] = Bi[((b*256 + c)<<12) + pix0 + p];
    }
    __syncthreads();
    int og = tid >> 3, pg = tid & 7;
    int o0 = og*4, p0 = pg*4;
    float acc[4][4];
    #pragma unroll
    for(int i=0;i<4;i++){ float bv=bias[o0+i];
        #pragma unroll
        for(int j=0;j<4;j++) acc[i][j]=bv; }
    for(int c=0;c<256;c++){
        float4 xv = *(const float4*)&sIn[(c<<5)+p0];
        float w0=w[(o0+0)*256+c], w1=w[(o0+1)*256+c];
        float w2=w[(o0+2)*256+c], w3=w[(o0+3)*256+c];
        acc[0][0]+=w0*xv.x; acc[0][1]+=w0*xv.y; acc[0][2]+=w0*xv.z; acc[0][3]+=w0*xv.w;
        acc[1][0]+=w1*xv.x; acc[1][1]+=w1*xv.y; acc[1][2]+=w1*xv.z; acc[1][3]+=w1*xv.w;
        acc[2][0]+=w2*xv.x; acc[2][1]+=w2*xv.y; acc[2][2]+=w2*xv.z; acc[2][3]+=w2*xv.w;
        acc[3][0]+=w3*xv.x; acc[3][1]+=w3*xv.y; acc[3][2]+=w3*xv.z; acc[3][3]+=w3*xv.w;
    }
    #pragma unroll
    for(int j=0;j<4;j++){
        int px = pix0 + p0 + j;
        *(float4*)&Ccl[((size_t)(b<<12) + px)*128 + o0] =
            make_float4(acc[0][j],acc[1][j],acc[2][j],acc[3][j]);
    }
}

// ---------------- K4: offset(18)+mask(9, sigmoid) 3x3 conv from Ccl -> OM (8,27,4096)
// Grid: 256 = 32 row-pairs x 8 b; b = blockIdx&7 for XCD L2 affinity.
__global__ __launch_bounds__(256) void k_offmask(fp Ccl, fp pw, fp pb, fp mw, fp mb, float* OM){
    __shared__ float sX[4*16*68];    // [(row*16+c)][68], rows 272B (16B-aligned)
    __shared__ float sW[16*9*30];    // [(c*9+tap)*30 + q], stride 30: 2-way banks, 8B-aligned
    int b = blockIdx.x & 7;
    int y0 = (blockIdx.x >> 3) << 1;
    int tid = threadIdx.x;
    int qp = tid >> 4, pxg = tid & 15;
    int q0 = qp << 1;                 // 0..30
    int ry = pxg >> 3;                // which of the 2 output rows
    int x0 = (pxg & 7) << 3;          // 0..56
    const float* cb = Ccl + (size_t)(b<<12)*128;
    float acc[2][8] = {{0.f}};

    for(int chunk=0; chunk<8; chunk++){
        int c0 = chunk << 4;
        __syncthreads();
        for(int j=tid; j<1088; j+=256){
            int cg = j & 3; int t = j >> 2; int pxh = t % 68; int row = t / 68;
            int yy = y0 + row - 1; int xx = pxh - 1;
            float4 v = make_float4(0.f,0.f,0.f,0.f);
            if(yy>=0 && yy<64 && xx>=0 && xx<64)
                v = *(const float4*)&cb[(size_t)((yy<<6)+xx)*128 + c0 + (cg<<2)];
            int ci = (row*16 + (cg<<2))*68 + pxh;
            sX[ci] = v.x; sX[ci+68] = v.y; sX[ci+136] = v.z; sX[ci+204] = v.w;
        }
        for(int j=tid; j<3888; j+=256){
            int qq = j / 144; int rem = j - qq*144;    // rem = c*9+tap
            float wv = (qq<18) ? pw[qq*1152 + c0*9 + rem]
                               : mw[(qq-18)*1152 + c0*9 + rem];
            sW[rem*30 + qq] = wv;
        }
        __syncthreads();
        for(int ci=0; ci<16; ci++){
            #pragma unroll
            for(int ky=0; ky<3; ky++){
                const float* xr = &sX[(((ry+ky)*16 + ci)*68) + x0];
                float xv[10];
                *(float4*)&xv[0] = *(const float4*)&xr[0];
                *(float4*)&xv[4] = *(const float4*)&xr[4];
                *(float2*)&xv[8] = *(const float2*)&xr[8];
                const float* wb = &sW[(ci*9 + ky*3)*30 + q0];
                float2 w0 = *(const float2*)&wb[0];
                float2 w1 = *(const float2*)&wb[30];
                float2 w2 = *(const float2*)&wb[60];
                #pragma unroll
                for(int j=0;j<8;j++){
                    acc[0][j] += w0.x*xv[j] + w1.x*xv[j+1] + w2.x*xv[j+2];
                    acc[1][j] += w0.y*xv[j] + w1.y*xv[j+1] + w2.y*xv[j+2];
                }
            }
        }
    }
    #pragma unroll
    for(int qi=0; qi<2; qi++){
        int q = q0 + qi;
        if(q >= 27) continue;
        float bias = (q<18) ? pb[q] : mb[q-18];
        float o[8];
        #pragma unroll
        for(int j=0;j<8;j++){
            float v = acc[qi][j] + bias;
            o[j] = (q>=18) ? 1.f/(1.f+expf(-v)) : v;
        }
        float* dst = OM + ((b*27+q)<<12) + ((y0+ry)<<6) + x0;
        *(float4*)dst     = make_float4(o[0],o[1],o[2],o[3]);
        *(float4*)(dst+4) = make_float4(o[4],o[5],o[6],o[7]);
    }
}

// ---------------- K5: deformable sampling + f32 FMA combine, convoy-broken version.
// Grid: 1024 = 128 px-tiles(32 px) x 8 b; b = blockIdx&7 (XCD L2 affinity).
// All-tap meta precomputed; per tap: prefetch next tap's 16 corner float4 into regs,
// FMA on current LDS buffer (global loads in flight under it), combine+store to other
// buffer, ONE barrier. Tap order rotated per tile to de-phase co-resident blocks.
__global__ __launch_bounds__(256) void k_deform(fp Ccl, fp OM, fp Wt2, float* D){
    __shared__ float sXf[2][128*34];  // [buf][c][px], stride 34
    __shared__ int   sBase[9*128];    // [n][px*4+corner]
    __shared__ float sGw[9*128];
    int b = blockIdx.x & 7;
    int tile = blockIdx.x >> 3;       // 0..127
    int pix0 = tile << 5;
    int tid = threadIdx.x;
    int og = tid >> 3, pg = tid & 7;
    int o0 = og*4, p0 = pg*4;
    const float* omb = OM + b*27*4096;
    const float* cb  = Ccl + (size_t)(b<<12)*128;
    float acc[4][4] = {{0.f}};
    int rot = tile % 9;

    // ---- meta for all 9 taps (288 items: 9 n x 32 px)
    for(int i = tid; i < 288; i += 256){
        int n = i >> 5, t = i & 31;
        int pix = pix0 + t, y = pix>>6, x = pix&63;
        float offx = omb[(n<<12)+pix];
        float offy = omb[((n+9)<<12)+pix];
        float m    = omb[((n+18)<<12)+pix];
        float pxf = (float)(y + n/3) + offx;     // (y+1)+(n/3-1)
        float pyf = (float)(x + n%3) + offy;     // (x+1)+(n%3-1)
        float fx = floorf(pxf), fy = floorf(pyf);
        float qx0 = fminf(fmaxf(fx,0.f),65.f), qx1 = fminf(fmaxf(fx+1.f,0.f),65.f);
        float qy0 = fminf(fmaxf(fy,0.f),65.f), qy1 = fminf(fmaxf(fy+1.f,0.f),65.f);
        float pxc = fminf(fmaxf(pxf,0.f),65.f), pyc = fminf(fmaxf(pyf,0.f),65.f);
        float glt = (1.f+(qx0-pxc))*(1.f+(qy0-pyc))*m;
        float grb = (1.f-(qx1-pxc))*(1.f-(qy1-pyc))*m;
        float glb = (1.f+(qx0-pxc))*(1.f-(qy1-pyc))*m;
        float grt = (1.f-(qx1-pxc))*(1.f+(qy0-pyc))*m;
        int ax0=(int)qx0, ax1=(int)qx1, ay0=(int)qy0, ay1=(int)qy1;
        int base = (n<<7) + (t<<2);
        sBase[base+0] = (ax0>=1&&ax0<=64&&ay0>=1&&ay0<=64) ? (((ax0-1)<<6)+(ay0-1)) : -1;
        sBase[base+1] = (ax1>=1&&ax1<=64&&ay1>=1&&ay1<=64) ? (((ax1-1)<<6)+(ay1-1)) : -1;
        sBase[base+2] = (ax0>=1&&ax0<=64&&ay1>=1&&ay1<=64) ? (((ax0-1)<<6)+(ay1-1)) : -1;
        sBase[base+3] = (ax1>=1&&ax1<=64&&ay0>=1&&ay0<=64) ? (((ax1-1)<<6)+(ay0-1)) : -1;
        sGw[base+0]=glt; sGw[base+1]=grb; sGw[base+2]=glb; sGw[base+3]=grt;
    }
    __syncthreads();

    float4 r[4][4];
    // thread's fixed gather coords: e = tid + it*256 -> cg=(e>>5)*4, px=e&31
    int gcg[4], gpx[4];
    #pragma unroll
    for(int it=0; it<4; it++){
        int e = tid + (it<<8);
        gcg[it] = (e >> 5) << 2; gpx[it] = e & 31;
    }

    // prologue: gather tap 'rot' straight into buf 0
    #pragma unroll
    for(int it=0; it<4; it++){
        const int* bp = &sBase[(rot<<7) + (gpx[it]<<2)];
        const float* gp = &sGw[(rot<<7) + (gpx[it]<<2)];
        float4 v = make_float4(0.f,0.f,0.f,0.f);
        #pragma unroll
        for(int k=0;k<4;k++){
            int bs = bp[k];
            if(bs>=0){
                float g = gp[k];
                float4 rr = *(const float4*)&cb[(bs<<7) + gcg[it]];
                v.x += g*rr.x; v.y += g*rr.y; v.z += g*rr.z; v.w += g*rr.w;
            }
        }
        sXf[0][(gcg[it]+0)*34+gpx[it]]=v.x; sXf[0][(gcg[it]+1)*34+gpx[it]]=v.y;
        sXf[0][(gcg[it]+2)*34+gpx[it]]=v.z; sXf[0][(gcg[it]+3)*34+gpx[it]]=v.w;
    }
    __syncthreads();

    for(int i=0;i<9;i++){
        int cur = rot + i; if(cur>=9) cur-=9;
        int nxt = cur + 1; if(nxt>=9) nxt-=9;
        int buf = i & 1;
        // prefetch next tap's corners into regs (loads stay in flight under FMA)
        if(i<8){
            #pragma unroll
            for(int it=0; it<4; it++){
                const int* bp = &sBase[(nxt<<7) + (gpx[it]<<2)];
                #pragma unroll
                for(int k=0;k<4;k++){
                    int bs = bp[k];
                    r[it][k] = (bs>=0) ? *(const float4*)&cb[(bs<<7) + gcg[it]]
                                       : make_float4(0.f,0.f,0.f,0.f);
                }
            }
        }
        // FMA on current buffer
        const float* wn = Wt2 + (cur<<14);
        const float* xb = &sXf[buf][0];
        for(int c=0;c<128;c++){
            float4 w4 = *(const float4*)&wn[(c<<7)+o0];
            float4 xa = *(const float4*)&xb[c*34+p0];
            acc[0][0]+=w4.x*xa.x; acc[0][1]+=w4.x*xa.y; acc[0][2]+=w4.x*xa.z; acc[0][3]+=w4.x*xa.w;
            acc[1][0]+=w4.y*xa.x; acc[1][1]+=w4.y*xa.y; acc[1][2]+=w4.y*xa.z; acc[1][3]+=w4.y*xa.w;
            acc[2][0]+=w4.z*xa.x; acc[2][1]+=w4.z*xa.y; acc[2][2]+=w4.z*xa.z; acc[2][3]+=w4.z*xa.w;
            acc[3][0]+=w4.w*xa.x; acc[3][1]+=w4.w*xa.y; acc[3][2]+=w4.w*xa.z; acc[3][3]+=w4.w*xa.w;
        }
        // combine + store prefetched tap into the other buffer
        if(i<8){
            #pragma unroll
            for(int it=0; it<4; it++){
                const float* gp = &sGw[(nxt<<7) + (gpx[it]<<2)];
                float4 v = make_float4(0.f,0.f,0.f,0.f);
                #pragma unroll
                for(int k=0;k<4;k++){
                    float g = gp[k];   // r is 0 for OOB corners
                    v.x += g*r[it][k].x; v.y += g*r[it][k].y;
                    v.z += g*r[it][k].z; v.w += g*r[it][k].w;
                }
                float* dst = &sXf[buf^1][0];
                dst[(gcg[it]+0)*34+gpx[it]]=v.x; dst[(gcg[it]+1)*34+gpx[it]]=v.y;
                dst[(gcg[it]+2)*34+gpx[it]]=v.z; dst[(gcg[it]+3)*34+gpx[it]]=v.w;
            }
        }
        __syncthreads();
    }
    #pragma unroll
    for(int i=0;i<4;i++){
        *(float4*)&D[((b*128+o0+i)<<12)+pix0+p0] =
            make_float4(acc[i][0],acc[i][1],acc[i][2],acc[i][3]);
    }
}

// ---------------- stats: per-channel mean & rstd (training BN, biased var)
__global__ __launch_bounds__(256) void k_stats(const float* src, float* stats, int statOfs){
    __shared__ double sd[256], sq[256];
    int c = blockIdx.x, tid = threadIdx.x;
    double s=0.0, s2=0.0;
    for(int b=0;b<8;b++){
        const float* p = src + ((b*128+c)<<12);
        for(int i=tid;i<4096;i+=256){ double v = (double)p[i]; s+=v; s2+=v*v; }
    }
    sd[tid]=s; sq[tid]=s2; __syncthreads();
    for(int off=128; off>0; off>>=1){
        if(tid<off){ sd[tid]+=sd[tid+off]; sq[tid]+=sq[tid+off]; }
        __syncthreads();
    }
    if(tid==0){
        double mean = sd[0]/32768.0;
        double var  = sq[0]/32768.0 - mean*mean;
        stats[statOfs+c]     = (float)mean;
        stats[statOfs+128+c] = rsqrtf((float)var + 1e-5f);
    }
}

// ---------------- BN1 + exact GELU
__global__ __launch_bounds__(256) void k_bn_gelu(const float* D, const float* stats, fp g, fp bb, float* G){
    int idx = blockIdx.x*256+threadIdx.x;       // 4,194,304
    int c = (idx>>12)&127;
    float v = (D[idx]-stats[c])*stats[128+c]*g[c] + bb[c];
    G[idx] = 0.5f*v*(1.0f+erff(v*0.70710678118654752f));
}

// ---------------- depthwise 3x3 over 128 ch + bias
__global__ __launch_bounds__(256) void k_dw128(const float* G, fp w, fp bias, float* Hs){
    int idx = blockIdx.x*256 + threadIdx.x;     // 4,194,304
    int x = idx&63, y=(idx>>6)&63, c=(idx>>12)&127, b=idx>>19;
    const float* src = G + ((b*128+c)<<12);
    float acc = bias[c];
    #pragma unroll
    for(int ky=0; ky<3; ky++){
        int yy = y+ky-1; if(yy<0||yy>63) continue;
        #pragma unroll
        for(int kx=0; kx<3; kx++){
            int xx = x+kx-1; if(xx<0||xx>63) continue;
            acc += src[(yy<<6)+xx]*w[c*9+ky*3+kx];
        }
    }
    Hs[idx] = acc;
}

// ---------------- BN2 + ReLU -> f32 out
__global__ __launch_bounds__(256) void k_bn_relu_out(const float* Hs, const float* stats, fp g, fp bb, float* out){
    int idx = blockIdx.x*256+threadIdx.x;       // 4,194,304
    int c = (idx>>12)&127;
    float v = (Hs[idx]-stats[256+c])*stats[384+c]*g[c] + bb[c];
    out[idx] = fmaxf(v,0.f);
}

extern "C" void kernel_launch(void* const* d_in, const int* in_sizes, int n_in,
                              void* d_out, int out_size, void* d_ws, size_t ws_size,
                              hipStream_t stream){
    fp x1   = (fp)d_in[0];
    fp x2   = (fp)d_in[1];
    fp dw_w = (fp)d_in[2];  fp dw_b = (fp)d_in[3];
    fp pw_w = (fp)d_in[4];  fp pw_b = (fp)d_in[5];
    fp p_w  = (fp)d_in[6];  fp p_b  = (fp)d_in[7];
    fp m_w  = (fp)d_in[8];  fp m_b  = (fp)d_in[9];
    fp dcn_w= (fp)d_in[10];
    fp bn1g = (fp)d_in[11]; fp bn1b = (fp)d_in[12];
    fp dw2w = (fp)d_in[13]; fp dw2b = (fp)d_in[14];
    fp bn2g = (fp)d_in[15]; fp bn2b = (fp)d_in[16];

    float* ws    = (float*)d_ws;
    float* A     = ws;                  // 8,388,608 f  (xcat; later OM+Ccl / G+Hs)
    float* Bo    = ws + 8388608;        // 8,388,608 f  (xdw;  later D)
    float* Wt2   = ws + 20971520;       //   147,456 f  (tap-major dcn_w)
    float* stats = ws + 21118976;       //       512 f
    float* OM  = A;                     // (8,27,4096) = 884,736 f
    float* Ccl = A + 2097152;           // (8,4096,128) ch-last = 4,194,304 f
    float* D   = Bo;                    // (8,128,4096)
    float* G   = A;                     // post-BN1 GELU (OM/Ccl dead)
    float* Hs  = A + 4194304;
    float* out = (float*)d_out;

    k_wt2       <<<576,   256, 0, stream>>>(dcn_w, Wt2);
    k_concat_up <<<32768, 256, 0, stream>>>(x1, x2, A);
    k_dw256     <<<32768, 256, 0, stream>>>(A, dw_w, dw_b, Bo);
    k_pw        <<<1024,  256, 0, stream>>>(Bo, pw_w, pw_b, Ccl);
    k_offmask   <<<256,   256, 0, stream>>>(Ccl, p_w, p_b, m_w, m_b, OM);
    k_deform    <<<1024,  256, 0, stream>>>(Ccl, OM, Wt2, D);
    k_stats     <<<128,   256, 0, stream>>>(D, stats, 0);
    k_bn_gelu   <<<16384, 256, 0, stream>>>(D, stats, bn1g, bn1b, G);
    k_dw128     <<<16384, 256, 0, stream>>>(G, dw2w, dw2b, Hs);
    k_stats     <<<128,   256, 0, stream>>>(Hs, stats, 256);
    k_bn_relu_out<<<16384,256, 0, stream>>>(Hs, stats, bn2g, bn2b, out);
}

// Round 8
// 531.742 us; speedup vs baseline: 1.3713x; 1.3713x over previous
//
#include <hip/hip_runtime.h>
#include <math.h>

// Problem constants: B=8, spatial 64x64 (HW=4096), C_mid=256, C=128, N=9 taps.
// All inputs/outputs are float32.
typedef const float* fp;
typedef __attribute__((ext_vector_type(8))) short short8;   // 8 bf16 = 4 VGPRs (MFMA A/B frag)
typedef __attribute__((ext_vector_type(4))) float f32x4;    // MFMA C/D frag

__device__ __forceinline__ unsigned short f2bf(float f){    // RTNE float->bf16
    unsigned u = __float_as_uint(f);
    u += 0x7fff + ((u >> 16) & 1);
    return (unsigned short)(u >> 16);
}

// ---------------- K0: dcn_w (o,c,9) -> Wbf[n][o][c] bf16
__global__ __launch_bounds__(256) void k_wbf(fp dcn_w, unsigned short* Wbf){
    int i = blockIdx.x*256 + threadIdx.x;       // 147456
    int c = i & 127, o = (i >> 7) & 127, n = i >> 14;
    Wbf[i] = f2bf(dcn_w[o*1152 + c*9 + n]);
}

// ---------------- K1: bilinear up2x(align_corners) of x1 + concat with x2 -> A (8,256,64,64)
__global__ __launch_bounds__(256) void k_concat_up(fp x1, fp x2, float* A){
    int idx = blockIdx.x*256 + threadIdx.x;     // 8,388,608
    int x = idx & 63, y = (idx>>6)&63, c = (idx>>12)&255, b = idx>>20;
    float val;
    if (c < 128){
        val = x2[((b*128+c)<<12) + (y<<6) + x];
    } else {
        int cc = c - 128;
        const float s = 31.0f/63.0f;
        float fy = y*s, fx = x*s;
        int iy = (int)fy; if (iy > 30) iy = 30;
        int ix = (int)fx; if (ix > 30) ix = 30;
        float ty = fy - (float)iy, tx = fx - (float)ix;
        fp src = x1 + ((b*128+cc)<<10);
        float v00 = src[iy*32+ix],     v01 = src[iy*32+ix+1];
        float v10 = src[(iy+1)*32+ix], v11 = src[(iy+1)*32+ix+1];
        val = (v00*(1.f-ty)+v10*ty)*(1.f-tx) + (v01*(1.f-ty)+v11*ty)*tx;
    }
    A[idx] = val;
}

// ---------------- K2: depthwise 3x3 SAME over 256 ch + bias -> Bo
__global__ __launch_bounds__(256) void k_dw256(const float* A, fp w, fp bias, float* Bo){
    int idx = blockIdx.x*256 + threadIdx.x;     // 8,388,608
    int x = idx&63, y=(idx>>6)&63, c=(idx>>12)&255, b=idx>>20;
    const float* src = A + ((b*256+c)<<12);
    float acc = bias[c];
    #pragma unroll
    for(int ky=0; ky<3; ky++){
        int yy = y+ky-1; if(yy<0||yy>63) continue;
        #pragma unroll
        for(int kx=0; kx<3; kx++){
            int xx = x+kx-1; if(xx<0||xx>63) continue;
            acc += src[(yy<<6)+xx]*w[c*9+ky*3+kx];
        }
    }
    Bo[idx] = acc;
}

// ---------------- K3: pointwise 256->128 + bias -> Ccl (channel-last only)
__global__ __launch_bounds__(256) void k_pw(const float* Bi, fp w, fp bias, float* Ccl){
    __shared__ float sIn[256*32];
    int bid = blockIdx.x;                       // 1024
    int b = bid >> 7;
    int pix0 = (bid & 127) << 5;
    int tid = threadIdx.x;
    for(int j = tid; j < 256*32; j += 256){
        int c = j >> 5, p = j & 31;
        sIn[j] = Bi[((b*256 + c)<<12) + pix0 + p];
    }
    __syncthreads();
    int og = tid >> 3, pg = tid & 7;
    int o0 = og*4, p0 = pg*4;
    float acc[4][4];
    #pragma unroll
    for(int i=0;i<4;i++){ float bv=bias[o0+i];
        #pragma unroll
        for(int j=0;j<4;j++) acc[i][j]=bv; }
    for(int c=0;c<256;c++){
        float4 xv = *(const float4*)&sIn[(c<<5)+p0];
        float w0=w[(o0+0)*256+c], w1=w[(o0+1)*256+c];
        float w2=w[(o0+2)*256+c], w3=w[(o0+3)*256+c];
        acc[0][0]+=w0*xv.x; acc[0][1]+=w0*xv.y; acc[0][2]+=w0*xv.z; acc[0][3]+=w0*xv.w;
        acc[1][0]+=w1*xv.x; acc[1][1]+=w1*xv.y; acc[1][2]+=w1*xv.z; acc[1][3]+=w1*xv.w;
        acc[2][0]+=w2*xv.x; acc[2][1]+=w2*xv.y; acc[2][2]+=w2*xv.z; acc[2][3]+=w2*xv.w;
        acc[3][0]+=w3*xv.x; acc[3][1]+=w3*xv.y; acc[3][2]+=w3*xv.z; acc[3][3]+=w3*xv.w;
    }
    #pragma unroll
    for(int j=0;j<4;j++){
        int px = pix0 + p0 + j;
        *(float4*)&Ccl[((size_t)(b<<12) + px)*128 + o0] =
            make_float4(acc[0][j],acc[1][j],acc[2][j],acc[3][j]);
    }
}

// ---------------- K4: offset(18)+mask(9, sigmoid) 3x3 conv from Ccl -> OM (8,27,4096)
__global__ __launch_bounds__(256) void k_offmask(fp Ccl, fp pw, fp pb, fp mw, fp mb, float* OM){
    __shared__ float sX[4*16*68];
    __shared__ float sW[16*9*30];
    int b = blockIdx.x & 7;
    int y0 = (blockIdx.x >> 3) << 1;
    int tid = threadIdx.x;
    int qp = tid >> 4, pxg = tid & 15;
    int q0 = qp << 1;
    int ry = pxg >> 3;
    int x0 = (pxg & 7) << 3;
    const float* cb = Ccl + (size_t)(b<<12)*128;
    float acc[2][8] = {{0.f}};

    for(int chunk=0; chunk<8; chunk++){
        int c0 = chunk << 4;
        __syncthreads();
        for(int j=tid; j<1088; j+=256){
            int cg = j & 3; int t = j >> 2; int pxh = t % 68; int row = t / 68;
            int yy = y0 + row - 1; int xx = pxh - 1;
            float4 v = make_float4(0.f,0.f,0.f,0.f);
            if(yy>=0 && yy<64 && xx>=0 && xx<64)
                v = *(const float4*)&cb[(size_t)((yy<<6)+xx)*128 + c0 + (cg<<2)];
            int ci = (row*16 + (cg<<2))*68 + pxh;
            sX[ci] = v.x; sX[ci+68] = v.y; sX[ci+136] = v.z; sX[ci+204] = v.w;
        }
        for(int j=tid; j<3888; j+=256){
            int qq = j / 144; int rem = j - qq*144;
            float wv = (qq<18) ? pw[qq*1152 + c0*9 + rem]
                               : mw[(qq-18)*1152 + c0*9 + rem];
            sW[rem*30 + qq] = wv;
        }
        __syncthreads();
        for(int ci=0; ci<16; ci++){
            #pragma unroll
            for(int ky=0; ky<3; ky++){
                const float* xr = &sX[(((ry+ky)*16 + ci)*68) + x0];
                float xv[10];
                *(float4*)&xv[0] = *(const float4*)&xr[0];
                *(float4*)&xv[4] = *(const float4*)&xr[4];
                *(float2*)&xv[8] = *(const float2*)&xr[8];
                const float* wb = &sW[(ci*9 + ky*3)*30 + q0];
                float2 w0 = *(const float2*)&wb[0];
                float2 w1 = *(const float2*)&wb[30];
                float2 w2 = *(const float2*)&wb[60];
                #pragma unroll
                for(int j=0;j<8;j++){
                    acc[0][j] += w0.x*xv[j] + w1.x*xv[j+1] + w2.x*xv[j+2];
                    acc[1][j] += w0.y*xv[j] + w1.y*xv[j+1] + w2.y*xv[j+2];
                }
            }
        }
    }
    #pragma unroll
    for(int qi=0; qi<2; qi++){
        int q = q0 + qi;
        if(q >= 27) continue;
        float bias = (q<18) ? pb[q] : mb[q-18];
        float o[8];
        #pragma unroll
        for(int j=0;j<8;j++){
            float v = acc[qi][j] + bias;
            o[j] = (q>=18) ? 1.f/(1.f+expf(-v)) : v;
        }
        float* dst = OM + ((b*27+q)<<12) + ((y0+ry)<<6) + x0;
        *(float4*)dst     = make_float4(o[0],o[1],o[2],o[3]);
        *(float4*)(dst+4) = make_float4(o[4],o[5],o[6],o[7]);
    }
}

// ---------------- K5: deformable sampling + bf16 MFMA combine (self-probing D layout).
// Grid: 1024 = 128 px-tiles(32 px) x 8 b; b = blockIdx&7 (XCD L2 affinity).
// Block: 128 o x 32 px; wave = 64 o x 16 px -> 4 acc frags of 16x16.
// Per tap: meta (tid<32) + stage W tile; gather 32px x 128c -> bf16 sX; 4 k-steps MFMA.
// Runtime probe MFMA resolves whether the C/D frag is (row=quad*4+r, col=lane&15)
// or transposed, and the epilogue writes accordingly — correct under either convention.
__global__ __launch_bounds__(256) void k_deform(fp Ccl, fp OM, const unsigned short* Wbf, float* D){
    __shared__ __align__(16) unsigned short sW[128*136];  // [o][c] bf16, stride 272B
    __shared__ __align__(16) unsigned short sX[32*136];   // [px][c] bf16
    __shared__ int   sBase[32*4];
    __shared__ float sGw[32*4];
    int b = blockIdx.x & 7;
    int pix0 = (blockIdx.x >> 3) << 5;
    int tid = threadIdx.x;
    int lane = tid & 63, wave = tid >> 6;
    int m16 = lane & 15, quad = lane >> 4;
    int wo = (wave & 1) << 6;       // o-half: 0/64
    int wp = (wave >> 1) << 4;      // px-half: 0/16
    const float* omb = OM + b*27*4096;
    const float* cb  = Ccl + (size_t)(b<<12)*128;

    // ---- probe: A[m][k]=delta(k==0)*m ; B[k][n]=delta(k==0)*(n+100) -> D[m][n]=m*(n+100)
    short8 ap = {0,0,0,0,0,0,0,0}, bpr = {0,0,0,0,0,0,0,0};
    if(quad == 0){
        ap[0]  = (short)f2bf((float)m16);
        bpr[0] = (short)f2bf((float)(m16+100));
    }
    f32x4 dp = {0.f,0.f,0.f,0.f};
    dp = __builtin_amdgcn_mfma_f32_16x16x32_bf16(ap, bpr, dp, 0,0,0);
    bool p1 = true;
    #pragma unroll
    for(int r=0;r<4;r++){
        float expP1 = (float)(quad*4+r) * (float)(m16+100);
        p1 = p1 && (fabsf(dp[r]-expP1) < 0.5f);
    }
    bool swapD = (__ballot(p1) != 0xFFFFFFFFFFFFFFFFull);

    f32x4 acc[4];
    #pragma unroll
    for(int i=0;i<4;i++) acc[i] = (f32x4){0.f,0.f,0.f,0.f};

    for(int n=0;n<9;n++){
        __syncthreads();                 // prev MFMA reads done before sW/sX/meta overwrite
        if(tid < 32){                    // sampling meta, one thread per px
            int pix = pix0 + tid, y = pix>>6, x = pix&63;
            float offx = omb[(n<<12)+pix];
            float offy = omb[((n+9)<<12)+pix];
            float m    = omb[((n+18)<<12)+pix];
            float pxf = (float)(y + n/3) + offx;     // (y+1)+(n/3-1)
            float pyf = (float)(x + n%3) + offy;     // (x+1)+(n%3-1)
            float fx = floorf(pxf), fy = floorf(pyf);
            float qx0 = fminf(fmaxf(fx,0.f),65.f), qx1 = fminf(fmaxf(fx+1.f,0.f),65.f);
            float qy0 = fminf(fmaxf(fy,0.f),65.f), qy1 = fminf(fmaxf(fy+1.f,0.f),65.f);
            float pxc = fminf(fmaxf(pxf,0.f),65.f), pyc = fminf(fmaxf(pyf,0.f),65.f);
            float glt = (1.f+(qx0-pxc))*(1.f+(qy0-pyc))*m;
            float grb = (1.f-(qx1-pxc))*(1.f-(qy1-pyc))*m;
            float glb = (1.f+(qx0-pxc))*(1.f-(qy1-pyc))*m;
            float grt = (1.f-(qx1-pxc))*(1.f+(qy0-pyc))*m;
            int ax0=(int)qx0, ax1=(int)qx1, ay0=(int)qy0, ay1=(int)qy1;
            sBase[tid*4+0] = (ax0>=1&&ax0<=64&&ay0>=1&&ay0<=64) ? (((ax0-1)<<6)+(ay0-1)) : -1;
            sBase[tid*4+1] = (ax1>=1&&ax1<=64&&ay1>=1&&ay1<=64) ? (((ax1-1)<<6)+(ay1-1)) : -1;
            sBase[tid*4+2] = (ax0>=1&&ax0<=64&&ay1>=1&&ay1<=64) ? (((ax0-1)<<6)+(ay1-1)) : -1;
            sBase[tid*4+3] = (ax1>=1&&ax1<=64&&ay0>=1&&ay0<=64) ? (((ax1-1)<<6)+(ay0-1)) : -1;
            sGw[tid*4+0]=glt; sGw[tid*4+1]=grb; sGw[tid*4+2]=glb; sGw[tid*4+3]=grt;
        }
        {   // stage weight tile sW[o][c] = Wbf[n][o][c]  (32KB, int4 copies)
            const int4* src = (const int4*)(Wbf + (n<<14));
            for(int j = tid; j < 2048; j += 256){
                int o = j >> 4, cg = j & 15;
                *(int4*)&sW[o*136 + (cg<<3)] = src[(o<<4) + cg];
            }
        }
        __syncthreads();
        // gather: 1024 = 32 cgroups x 32 px; combine 4 corners, pack bf16x4
        for(int e = tid; e < 1024; e += 256){
            int cg = (e >> 5) << 2, px = e & 31;
            const int* bp = &sBase[px<<2];
            const float* gp = &sGw[px<<2];
            float4 v = make_float4(0.f,0.f,0.f,0.f);
            #pragma unroll
            for(int k=0;k<4;k++){
                int bs = bp[k];
                if(bs>=0){
                    float g = gp[k];
                    float4 r = *(const float4*)&cb[(bs<<7) + cg];
                    v.x += g*r.x; v.y += g*r.y; v.z += g*r.z; v.w += g*r.w;
                }
            }
            unsigned long long pk = (unsigned long long)f2bf(v.x)
                | ((unsigned long long)f2bf(v.y)<<16)
                | ((unsigned long long)f2bf(v.z)<<32)
                | ((unsigned long long)f2bf(v.w)<<48);
            *(unsigned long long*)&sX[px*136 + cg] = pk;
        }
        __syncthreads();
        #pragma unroll
        for(int ks=0; ks<4; ks++){
            int k0 = ks << 5;
            short8 bfr = *(const short8*)&sX[(wp + m16)*136 + k0 + (quad<<3)];
            #pragma unroll
            for(int ot=0;ot<4;ot++){
                short8 afr = *(const short8*)&sW[(wo + (ot<<4) + m16)*136 + k0 + (quad<<3)];
                acc[ot] = __builtin_amdgcn_mfma_f32_16x16x32_bf16(afr, bfr, acc[ot], 0,0,0);
            }
        }
    }
    // epilogue: orientation per probe
    if(!swapD){
        #pragma unroll
        for(int ot=0;ot<4;ot++){
            int px = pix0 + wp + m16;
            #pragma unroll
            for(int r=0;r<4;r++){
                int o = wo + (ot<<4) + (quad<<2) + r;
                D[((b*128+o)<<12) + px] = acc[ot][r];
            }
        }
    } else {
        #pragma unroll
        for(int ot=0;ot<4;ot++){
            int o = wo + (ot<<4) + m16;
            #pragma unroll
            for(int r=0;r<4;r++){
                int px = pix0 + wp + (quad<<2) + r;
                D[((b*128+o)<<12) + px] = acc[ot][r];
            }
        }
    }
}

// ---------------- stats: per-channel mean & rstd (training BN, biased var)
__global__ __launch_bounds__(256) void k_stats(const float* src, float* stats, int statOfs){
    __shared__ double sd[256], sq[256];
    int c = blockIdx.x, tid = threadIdx.x;
    double s=0.0, s2=0.0;
    for(int b=0;b<8;b++){
        const float* p = src + ((b*128+c)<<12);
        for(int i=tid;i<4096;i+=256){ double v = (double)p[i]; s+=v; s2+=v*v; }
    }
    sd[tid]=s; sq[tid]=s2; __syncthreads();
    for(int off=128; off>0; off>>=1){
        if(tid<off){ sd[tid]+=sd[tid+off]; sq[tid]+=sq[tid+off]; }
        __syncthreads();
    }
    if(tid==0){
        double mean = sd[0]/32768.0;
        double var  = sq[0]/32768.0 - mean*mean;
        stats[statOfs+c]     = (float)mean;
        stats[statOfs+128+c] = rsqrtf((float)var + 1e-5f);
    }
}

// ---------------- BN1 + exact GELU
__global__ __launch_bounds__(256) void k_bn_gelu(const float* D, const float* stats, fp g, fp bb, float* G){
    int idx = blockIdx.x*256+threadIdx.x;       // 4,194,304
    int c = (idx>>12)&127;
    float v = (D[idx]-stats[c])*stats[128+c]*g[c] + bb[c];
    G[idx] = 0.5f*v*(1.0f+erff(v*0.70710678118654752f));
}

// ---------------- depthwise 3x3 over 128 ch + bias
__global__ __launch_bounds__(256) void k_dw128(const float* G, fp w, fp bias, float* Hs){
    int idx = blockIdx.x*256 + threadIdx.x;     // 4,194,304
    int x = idx&63, y=(idx>>6)&63, c=(idx>>12)&127, b=idx>>19;
    const float* src = G + ((b*128+c)<<12);
    float acc = bias[c];
    #pragma unroll
    for(int ky=0; ky<3; ky++){
        int yy = y+ky-1; if(yy<0||yy>63) continue;
        #pragma unroll
        for(int kx=0; kx<3; kx++){
            int xx = x+kx-1; if(xx<0||xx>63) continue;
            acc += src[(yy<<6)+xx]*w[c*9+ky*3+kx];
        }
    }
    Hs[idx] = acc;
}

// ---------------- BN2 + ReLU -> f32 out
__global__ __launch_bounds__(256) void k_bn_relu_out(const float* Hs, const float* stats, fp g, fp bb, float* out){
    int idx = blockIdx.x*256+threadIdx.x;       // 4,194,304
    int c = (idx>>12)&127;
    float v = (Hs[idx]-stats[256+c])*stats[384+c]*g[c] + bb[c];
    out[idx] = fmaxf(v,0.f);
}

extern "C" void kernel_launch(void* const* d_in, const int* in_sizes, int n_in,
                              void* d_out, int out_size, void* d_ws, size_t ws_size,
                              hipStream_t stream){
    fp x1   = (fp)d_in[0];
    fp x2   = (fp)d_in[1];
    fp dw_w = (fp)d_in[2];  fp dw_b = (fp)d_in[3];
    fp pw_w = (fp)d_in[4];  fp pw_b = (fp)d_in[5];
    fp p_w  = (fp)d_in[6];  fp p_b  = (fp)d_in[7];
    fp m_w  = (fp)d_in[8];  fp m_b  = (fp)d_in[9];
    fp dcn_w= (fp)d_in[10];
    fp bn1g = (fp)d_in[11]; fp bn1b = (fp)d_in[12];
    fp dw2w = (fp)d_in[13]; fp dw2b = (fp)d_in[14];
    fp bn2g = (fp)d_in[15]; fp bn2b = (fp)d_in[16];

    float* ws    = (float*)d_ws;
    float* A     = ws;                  // 8,388,608 f  (xcat; later OM+Ccl / G+Hs)
    float* Bo    = ws + 8388608;        // 8,388,608 f  (xdw;  later D)
    unsigned short* Wbf = (unsigned short*)(ws + 20971520);  // 147,456 bf16
    float* stats = ws + 20971520 + 73728;                    // 512 f
    float* OM  = A;                     // (8,27,4096) = 884,736 f
    float* Ccl = A + 2097152;           // (8,4096,128) ch-last = 4,194,304 f
    float* D   = Bo;                    // (8,128,4096)
    float* G   = A;                     // post-BN1 GELU (OM/Ccl dead)
    float* Hs  = A + 4194304;
    float* out = (float*)d_out;

    k_wbf       <<<576,   256, 0, stream>>>(dcn_w, Wbf);
    k_concat_up <<<32768, 256, 0, stream>>>(x1, x2, A);
    k_dw256     <<<32768, 256, 0, stream>>>(A, dw_w, dw_b, Bo);
    k_pw        <<<1024,  256, 0, stream>>>(Bo, pw_w, pw_b, Ccl);
    k_offmask   <<<256,   256, 0, stream>>>(Ccl, p_w, p_b, m_w, m_b, OM);
    k_deform    <<<1024,  256, 0, stream>>>(Ccl, OM, Wbf, D);
    k_stats     <<<128,   256, 0, stream>>>(D, stats, 0);
    k_bn_gelu   <<<16384, 256, 0, stream>>>(D, stats, bn1g, bn1b, G);
    k_dw128     <<<16384, 256, 0, stream>>>(G, dw2w, dw2b, Hs);
    k_stats     <<<128,   256, 0, stream>>>(Hs, stats, 256);
    k_bn_relu_out<<<16384,256, 0, stream>>>(Hs, stats, bn2g, bn2b, out);
}

// Round 9
// 365.638 us; speedup vs baseline: 1.9942x; 1.4543x over previous
//
#include <hip/hip_runtime.h>
#include <math.h>

// Problem constants: B=8, spatial 64x64 (HW=4096), C_mid=256, C=128, N=9 taps.
// All inputs/outputs are float32.
typedef const float* fp;
typedef __attribute__((ext_vector_type(8))) short short8;   // 8 bf16 = 4 VGPRs (MFMA A/B frag)
typedef __attribute__((ext_vector_type(4))) float f32x4;    // MFMA C/D frag

__device__ __forceinline__ unsigned short f2bf(float f){    // RTNE float->bf16
    unsigned u = __float_as_uint(f);
    u += 0x7fff + ((u >> 16) & 1);
    return (unsigned short)(u >> 16);
}

// ---------------- K0: dcn_w (o,c,9) -> Wbf[n][o][c] bf16
__global__ __launch_bounds__(256) void k_wbf(fp dcn_w, unsigned short* Wbf){
    int i = blockIdx.x*256 + threadIdx.x;       // 147456
    int c = i & 127, o = (i >> 7) & 127, n = i >> 14;
    Wbf[i] = f2bf(dcn_w[o*1152 + c*9 + n]);
}

// ---------------- K1: fused upsample+concat+depthwise256 -> Bo (8,256,64,64)
// Grid 2048 = 8 b x 256 c. Block: one (b,c) plane; A-tile 66x66 (halo, pad-0) in LDS.
__global__ __launch_bounds__(256) void k_updw256(fp x1, fp x2, fp w, fp bias, float* Bo){
    __shared__ float sA[66*68];
    int bid = blockIdx.x;
    int c = bid & 255, b = bid >> 8;
    int tid = threadIdx.x;
    // fill A-tile: point (yy,xx) = (r-1, cpos-1), OOB -> 0
    for(int j = tid; j < 4356; j += 256){
        int r = j / 66, cpos = j - r*66;
        int yy = r - 1, xx = cpos - 1;
        float val = 0.f;
        if(yy >= 0 && yy < 64 && xx >= 0 && xx < 64){
            if(c < 128){
                val = x2[((b*128+c)<<12) + (yy<<6) + xx];
            } else {
                int cc = c - 128;
                const float s = 31.0f/63.0f;
                float fy = yy*s, fx = xx*s;
                int iy = (int)fy; if (iy > 30) iy = 30;
                int ix = (int)fx; if (ix > 30) ix = 30;
                float ty = fy - (float)iy, tx = fx - (float)ix;
                fp src = x1 + ((b*128+cc)<<10);
                float v00 = src[iy*32+ix],     v01 = src[iy*32+ix+1];
                float v10 = src[(iy+1)*32+ix], v11 = src[(iy+1)*32+ix+1];
                val = (v00*(1.f-ty)+v10*ty)*(1.f-tx) + (v01*(1.f-ty)+v11*ty)*tx;
            }
        }
        sA[r*68 + cpos] = val;
    }
    __syncthreads();
    float w0=w[c*9+0], w1=w[c*9+1], w2=w[c*9+2];
    float w3=w[c*9+3], w4=w[c*9+4], w5=w[c*9+5];
    float w6=w[c*9+6], w7=w[c*9+7], w8=w[c*9+8];
    float bv = bias[c];
    float* dst = Bo + ((size_t)(b*256+c)<<12);
    for(int j = tid; j < 4096; j += 256){
        int y = j >> 6, x = j & 63;
        const float* r0 = &sA[y*68 + x];
        float acc = bv
            + w0*r0[0]   + w1*r0[1]   + w2*r0[2]
            + w3*r0[68]  + w4*r0[69]  + w5*r0[70]
            + w6*r0[136] + w7*r0[137] + w8*r0[138];
        dst[j] = acc;
    }
}

// ---------------- K3: pointwise 256->128 + bias -> Ccl (channel-last only)
__global__ __launch_bounds__(256) void k_pw(const float* Bi, fp w, fp bias, float* Ccl){
    __shared__ float sIn[256*32];
    int bid = blockIdx.x;                       // 1024
    int b = bid >> 7;
    int pix0 = (bid & 127) << 5;
    int tid = threadIdx.x;
    for(int j = tid; j < 256*32; j += 256){
        int c = j >> 5, p = j & 31;
        sIn[j] = Bi[((b*256 + c)<<12) + pix0 + p];
    }
    __syncthreads();
    int og = tid >> 3, pg = tid & 7;
    int o0 = og*4, p0 = pg*4;
    float acc[4][4];
    #pragma unroll
    for(int i=0;i<4;i++){ float bv=bias[o0+i];
        #pragma unroll
        for(int j=0;j<4;j++) acc[i][j]=bv; }
    for(int c=0;c<256;c++){
        float4 xv = *(const float4*)&sIn[(c<<5)+p0];
        float w0=w[(o0+0)*256+c], w1=w[(o0+1)*256+c];
        float w2=w[(o0+2)*256+c], w3=w[(o0+3)*256+c];
        acc[0][0]+=w0*xv.x; acc[0][1]+=w0*xv.y; acc[0][2]+=w0*xv.z; acc[0][3]+=w0*xv.w;
        acc[1][0]+=w1*xv.x; acc[1][1]+=w1*xv.y; acc[1][2]+=w1*xv.z; acc[1][3]+=w1*xv.w;
        acc[2][0]+=w2*xv.x; acc[2][1]+=w2*xv.y; acc[2][2]+=w2*xv.z; acc[2][3]+=w2*xv.w;
        acc[3][0]+=w3*xv.x; acc[3][1]+=w3*xv.y; acc[3][2]+=w3*xv.z; acc[3][3]+=w3*xv.w;
    }
    #pragma unroll
    for(int j=0;j<4;j++){
        int px = pix0 + p0 + j;
        *(float4*)&Ccl[((size_t)(b<<12) + px)*128 + o0] =
            make_float4(acc[0][j],acc[1][j],acc[2][j],acc[3][j]);
    }
}

// ---------------- K4: offset(18)+mask(9, sigmoid) 3x3 conv from Ccl -> OM (8,27,4096)
__global__ __launch_bounds__(256) void k_offmask(fp Ccl, fp pw, fp pb, fp mw, fp mb, float* OM){
    __shared__ float sX[4*16*68];
    __shared__ float sW[16*9*30];
    int b = blockIdx.x & 7;
    int y0 = (blockIdx.x >> 3) << 1;
    int tid = threadIdx.x;
    int qp = tid >> 4, pxg = tid & 15;
    int q0 = qp << 1;
    int ry = pxg >> 3;
    int x0 = (pxg & 7) << 3;
    const float* cb = Ccl + (size_t)(b<<12)*128;
    float acc[2][8] = {{0.f}};

    for(int chunk=0; chunk<8; chunk++){
        int c0 = chunk << 4;
        __syncthreads();
        for(int j=tid; j<1088; j+=256){
            int cg = j & 3; int t = j >> 2; int pxh = t % 68; int row = t / 68;
            int yy = y0 + row - 1; int xx = pxh - 1;
            float4 v = make_float4(0.f,0.f,0.f,0.f);
            if(yy>=0 && yy<64 && xx>=0 && xx<64)
                v = *(const float4*)&cb[(size_t)((yy<<6)+xx)*128 + c0 + (cg<<2)];
            int ci = (row*16 + (cg<<2))*68 + pxh;
            sX[ci] = v.x; sX[ci+68] = v.y; sX[ci+136] = v.z; sX[ci+204] = v.w;
        }
        for(int j=tid; j<3888; j+=256){
            int qq = j / 144; int rem = j - qq*144;
            float wv = (qq<18) ? pw[qq*1152 + c0*9 + rem]
                               : mw[(qq-18)*1152 + c0*9 + rem];
            sW[rem*30 + qq] = wv;
        }
        __syncthreads();
        for(int ci=0; ci<16; ci++){
            #pragma unroll
            for(int ky=0; ky<3; ky++){
                const float* xr = &sX[(((ry+ky)*16 + ci)*68) + x0];
                float xv[10];
                *(float4*)&xv[0] = *(const float4*)&xr[0];
                *(float4*)&xv[4] = *(const float4*)&xr[4];
                *(float2*)&xv[8] = *(const float2*)&xr[8];
                const float* wb = &sW[(ci*9 + ky*3)*30 + q0];
                float2 w0 = *(const float2*)&wb[0];
                float2 w1 = *(const float2*)&wb[30];
                float2 w2 = *(const float2*)&wb[60];
                #pragma unroll
                for(int j=0;j<8;j++){
                    acc[0][j] += w0.x*xv[j] + w1.x*xv[j+1] + w2.x*xv[j+2];
                    acc[1][j] += w0.y*xv[j] + w1.y*xv[j+1] + w2.y*xv[j+2];
                }
            }
        }
    }
    #pragma unroll
    for(int qi=0; qi<2; qi++){
        int q = q0 + qi;
        if(q >= 27) continue;
        float bias = (q<18) ? pb[q] : mb[q-18];
        float o[8];
        #pragma unroll
        for(int j=0;j<8;j++){
            float v = acc[qi][j] + bias;
            o[j] = (q>=18) ? 1.f/(1.f+expf(-v)) : v;
        }
        float* dst = OM + ((b*27+q)<<12) + ((y0+ry)<<6) + x0;
        *(float4*)dst     = make_float4(o[0],o[1],o[2],o[3]);
        *(float4*)(dst+4) = make_float4(o[4],o[5],o[6],o[7]);
    }
}

// ---------------- K5: deformable sampling + bf16 MFMA combine, 64-px tiles.
// Grid 512 = 64 tiles x 8 b (b = blockIdx&7, XCD L2 affinity) -> 2 blocks/CU exactly.
// Block: 128 o x 64 px; wave = 64 o x 32 px -> 4x2 frags. All-tap meta precomputed.
// Gather is cg-fastest: coalesced 512B corner rows + conflict-free LDS b64 writes.
// Runtime MFMA probe resolves C/D orientation (proven in r8).
__global__ __launch_bounds__(256) void k_deform(fp Ccl, fp OM, const unsigned short* Wbf, float* D){
    __shared__ __align__(16) unsigned short sW[128*136];  // [o][c] bf16, 272B rows
    __shared__ __align__(16) unsigned short sX[64*136];   // [px][c] bf16
    __shared__ int   sBase[9*64*4];                        // [n][px][corner]
    __shared__ float sGw[9*64*4];
    int b = blockIdx.x & 7;
    int pix0 = (blockIdx.x >> 3) << 6;
    int tid = threadIdx.x;
    int lane = tid & 63, wave = tid >> 6;
    int m16 = lane & 15, quad = lane >> 4;
    int wo = (wave & 1) << 6;       // o-half: 0/64
    int wp = (wave >> 1) << 5;      // px-half: 0/32
    const float* omb = OM + b*27*4096;
    const float* cb  = Ccl + (size_t)(b<<12)*128;

    // ---- probe: A[m][k]=delta(k==0)*m ; B[k][n]=delta(k==0)*(n+100) -> D[m][n]=m*(n+100)
    short8 ap = {0,0,0,0,0,0,0,0}, bpr = {0,0,0,0,0,0,0,0};
    if(quad == 0){
        ap[0]  = (short)f2bf((float)m16);
        bpr[0] = (short)f2bf((float)(m16+100));
    }
    f32x4 dp = {0.f,0.f,0.f,0.f};
    dp = __builtin_amdgcn_mfma_f32_16x16x32_bf16(ap, bpr, dp, 0,0,0);
    bool p1 = true;
    #pragma unroll
    for(int r=0;r<4;r++){
        float expP1 = (float)(quad*4+r) * (float)(m16+100);
        p1 = p1 && (fabsf(dp[r]-expP1) < 0.5f);
    }
    bool swapD = (__ballot(p1) != 0xFFFFFFFFFFFFFFFFull);

    f32x4 acc[4][2];
    #pragma unroll
    for(int i=0;i<4;i++){
        #pragma unroll
        for(int j=0;j<2;j++) acc[i][j] = (f32x4){0.f,0.f,0.f,0.f};
    }

    // ---- meta for all 9 taps (576 = 9 n x 64 px)
    for(int i = tid; i < 576; i += 256){
        int n = i >> 6, t = i & 63;
        int pix = pix0 + t, y = pix>>6, x = pix&63;
        float offx = omb[(n<<12)+pix];
        float offy = omb[((n+9)<<12)+pix];
        float m    = omb[((n+18)<<12)+pix];
        float pxf = (float)(y + n/3) + offx;     // (y+1)+(n/3-1)
        float pyf = (float)(x + n%3) + offy;     // (x+1)+(n%3-1)
        float fx = floorf(pxf), fy = floorf(pyf);
        float qx0 = fminf(fmaxf(fx,0.f),65.f), qx1 = fminf(fmaxf(fx+1.f,0.f),65.f);
        float qy0 = fminf(fmaxf(fy,0.f),65.f), qy1 = fminf(fmaxf(fy+1.f,0.f),65.f);
        float pxc = fminf(fmaxf(pxf,0.f),65.f), pyc = fminf(fmaxf(pyf,0.f),65.f);
        float glt = (1.f+(qx0-pxc))*(1.f+(qy0-pyc))*m;
        float grb = (1.f-(qx1-pxc))*(1.f-(qy1-pyc))*m;
        float glb = (1.f+(qx0-pxc))*(1.f-(qy1-pyc))*m;
        float grt = (1.f-(qx1-pxc))*(1.f+(qy0-pyc))*m;
        int ax0=(int)qx0, ax1=(int)qx1, ay0=(int)qy0, ay1=(int)qy1;
        int base = i << 2;
        sBase[base+0] = (ax0>=1&&ax0<=64&&ay0>=1&&ay0<=64) ? (((ax0-1)<<6)+(ay0-1)) : -1;
        sBase[base+1] = (ax1>=1&&ax1<=64&&ay1>=1&&ay1<=64) ? (((ax1-1)<<6)+(ay1-1)) : -1;
        sBase[base+2] = (ax0>=1&&ax0<=64&&ay1>=1&&ay1<=64) ? (((ax0-1)<<6)+(ay1-1)) : -1;
        sBase[base+3] = (ax1>=1&&ax1<=64&&ay0>=1&&ay0<=64) ? (((ax1-1)<<6)+(ay0-1)) : -1;
        sGw[base+0]=glt; sGw[base+1]=grb; sGw[base+2]=glb; sGw[base+3]=grt;
    }
    __syncthreads();

    for(int n=0;n<9;n++){
        // stage weight tile sW[o][c] = Wbf[n][o][c]  (32KB, int4 copies)
        {
            const int4* src = (const int4*)(Wbf + (n<<14));
            for(int j = tid; j < 2048; j += 256){
                int o = j >> 4, cg = j & 15;
                *(int4*)&sW[o*136 + (cg<<3)] = src[(o<<4) + cg];
            }
        }
        // gather: 2048 = 64 px x 32 cgroups; cg fastest (coalesced + conflict-free)
        #pragma unroll
        for(int it=0; it<8; it++){
            int e = tid + (it<<8);
            int cg = (e & 31) << 2, px = e >> 5;
            int mb4 = ((n<<6) + px) << 2;
            const int* bp = &sBase[mb4];
            const float* gp = &sGw[mb4];
            float4 v = make_float4(0.f,0.f,0.f,0.f);
            #pragma unroll
            for(int k=0;k<4;k++){
                int bs = bp[k];
                if(bs>=0){
                    float g = gp[k];
                    float4 r = *(const float4*)&cb[(bs<<7) + cg];
                    v.x += g*r.x; v.y += g*r.y; v.z += g*r.z; v.w += g*r.w;
                }
            }
            unsigned long long pk = (unsigned long long)f2bf(v.x)
                | ((unsigned long long)f2bf(v.y)<<16)
                | ((unsigned long long)f2bf(v.z)<<32)
                | ((unsigned long long)f2bf(v.w)<<48);
            *(unsigned long long*)&sX[px*136 + cg] = pk;
        }
        __syncthreads();
        #pragma unroll
        for(int ks=0; ks<4; ks++){
            int k0 = ks << 5;
            short8 bfr[2];
            #pragma unroll
            for(int pt=0;pt<2;pt++)
                bfr[pt] = *(const short8*)&sX[(wp + (pt<<4) + m16)*136 + k0 + (quad<<3)];
            #pragma unroll
            for(int ot=0;ot<4;ot++){
                short8 afr = *(const short8*)&sW[(wo + (ot<<4) + m16)*136 + k0 + (quad<<3)];
                #pragma unroll
                for(int pt=0;pt<2;pt++)
                    acc[ot][pt] = __builtin_amdgcn_mfma_f32_16x16x32_bf16(afr, bfr[pt], acc[ot][pt], 0,0,0);
            }
        }
        __syncthreads();                 // MFMA reads done before next tap's overwrite
    }
    // epilogue: orientation per probe
    if(!swapD){
        #pragma unroll
        for(int ot=0;ot<4;ot++){
            #pragma unroll
            for(int pt=0;pt<2;pt++){
                int px = pix0 + wp + (pt<<4) + m16;
                #pragma unroll
                for(int r=0;r<4;r++){
                    int o = wo + (ot<<4) + (quad<<2) + r;
                    D[((b*128+o)<<12) + px] = acc[ot][pt][r];
                }
            }
        }
    } else {
        #pragma unroll
        for(int ot=0;ot<4;ot++){
            #pragma unroll
            for(int pt=0;pt<2;pt++){
                int o = wo + (ot<<4) + m16;
                #pragma unroll
                for(int r=0;r<4;r++){
                    int px = pix0 + wp + (pt<<4) + (quad<<2) + r;
                    D[((b*128+o)<<12) + px] = acc[ot][pt][r];
                }
            }
        }
    }
}

// ---------------- stats (parallel, atomic raw sums): src -> stats[ofs+c]=sum, stats[ofs+128+c]=sumsq
__global__ __launch_bounds__(256) void k_stats_par(const float* src, float* stats, int statOfs){
    __shared__ float sd[256], sq[256];
    int bid = blockIdx.x;                // 1024 = 8 b x 128 c
    int c = bid & 127, b = bid >> 7;
    int tid = threadIdx.x;
    const float* p = src + ((size_t)(b*128+c)<<12);
    float s = 0.f, s2 = 0.f;
    for(int i=tid; i<4096; i+=256){ float v = p[i]; s += v; s2 += v*v; }
    sd[tid]=s; sq[tid]=s2; __syncthreads();
    for(int off=128; off>0; off>>=1){
        if(tid<off){ sd[tid]+=sd[tid+off]; sq[tid]+=sq[tid+off]; }
        __syncthreads();
    }
    if(tid==0){
        atomicAdd(&stats[statOfs+c], sd[0]);
        atomicAdd(&stats[statOfs+128+c], sq[0]);
    }
}

// ---------------- K7: fused BN1+GELU + depthwise128 -> Hs, + atomic stats2 partials
// Grid 1024 = 8 b x 128 c. G-tile 66x66 (pad-0 AFTER gelu) in LDS.
__global__ __launch_bounds__(256) void k_bngelu_dw128(const float* Dsrc, float* stats,
                                                      fp g1, fp b1, fp w, fp bias, float* Hs){
    __shared__ float sG[66*68];
    __shared__ float sd[256], sq[256];
    int bid = blockIdx.x;
    int c = bid & 127, b = bid >> 7;
    int tid = threadIdx.x;
    float mean1 = stats[c] * (1.f/32768.f);
    float var1  = stats[128+c] * (1.f/32768.f) - mean1*mean1;
    float rstd1 = rsqrtf(var1 + 1e-5f);
    float sc = rstd1 * g1[c];
    float sb = b1[c] - mean1*sc;
    const float* dplane = Dsrc + ((size_t)(b*128+c)<<12);
    for(int j = tid; j < 4356; j += 256){
        int r = j / 66, cpos = j - r*66;
        int yy = r - 1, xx = cpos - 1;
        float val = 0.f;
        if(yy >= 0 && yy < 64 && xx >= 0 && xx < 64){
            float v = dplane[(yy<<6)+xx]*sc + sb;
            val = 0.5f*v*(1.0f + erff(v*0.70710678118654752f));
        }
        sG[r*68 + cpos] = val;
    }
    __syncthreads();
    float w0=w[c*9+0], w1=w[c*9+1], w2=w[c*9+2];
    float w3=w[c*9+3], w4=w[c*9+4], w5=w[c*9+5];
    float w6=w[c*9+6], w7=w[c*9+7], w8=w[c*9+8];
    float bv = bias[c];
    float* dst = Hs + ((size_t)(b*128+c)<<12);
    float s = 0.f, s2 = 0.f;
    for(int j = tid; j < 4096; j += 256){
        int y = j >> 6, x = j & 63;
        const float* r0 = &sG[y*68 + x];
        float acc = bv
            + w0*r0[0]   + w1*r0[1]   + w2*r0[2]
            + w3*r0[68]  + w4*r0[69]  + w5*r0[70]
            + w6*r0[136] + w7*r0[137] + w8*r0[138];
        dst[j] = acc;
        s += acc; s2 += acc*acc;
    }
    sd[tid]=s; sq[tid]=s2; __syncthreads();
    for(int off=128; off>0; off>>=1){
        if(tid<off){ sd[tid]+=sd[tid+off]; sq[tid]+=sq[tid+off]; }
        __syncthreads();
    }
    if(tid==0){
        atomicAdd(&stats[256+c], sd[0]);
        atomicAdd(&stats[384+c], sq[0]);
    }
}

// ---------------- BN2 + ReLU -> f32 out (finalizes stats2 sums inline)
__global__ __launch_bounds__(256) void k_bn_relu_out(const float* Hs, const float* stats, fp g, fp bb, float* out){
    int idx = blockIdx.x*256+threadIdx.x;       // 4,194,304
    int c = (idx>>12)&127;
    float mean2 = stats[256+c] * (1.f/32768.f);
    float var2  = stats[384+c] * (1.f/32768.f) - mean2*mean2;
    float rstd2 = rsqrtf(var2 + 1e-5f);
    float v = (Hs[idx]-mean2)*rstd2*g[c] + bb[c];
    out[idx] = fmaxf(v,0.f);
}

extern "C" void kernel_launch(void* const* d_in, const int* in_sizes, int n_in,
                              void* d_out, int out_size, void* d_ws, size_t ws_size,
                              hipStream_t stream){
    fp x1   = (fp)d_in[0];
    fp x2   = (fp)d_in[1];
    fp dw_w = (fp)d_in[2];  fp dw_b = (fp)d_in[3];
    fp pw_w = (fp)d_in[4];  fp pw_b = (fp)d_in[5];
    fp p_w  = (fp)d_in[6];  fp p_b  = (fp)d_in[7];
    fp m_w  = (fp)d_in[8];  fp m_b  = (fp)d_in[9];
    fp dcn_w= (fp)d_in[10];
    fp bn1g = (fp)d_in[11]; fp bn1b = (fp)d_in[12];
    fp dw2w = (fp)d_in[13]; fp dw2b = (fp)d_in[14];
    fp bn2g = (fp)d_in[15]; fp bn2b = (fp)d_in[16];

    float* ws  = (float*)d_ws;
    float* Bo  = ws;                    // (8,256,4096) = 8,388,608 f ; D reuses after k_pw
    float* Ccl = ws + 8388608;          // (8,4096,128) = 4,194,304 f ; Hs reuses after k_deform
    float* OM  = ws + 12582912;         // (8,27,4096)  =   884,736 f
    unsigned short* Wbf = (unsigned short*)(ws + 13467648);  // 147,456 bf16 (73,728 f)
    float* stats = ws + 13541376;       // 512 f (sum1, sq1, sum2, sq2)
    float* D   = Bo;                    // Bo dead after k_pw
    float* Hs  = Ccl;                   // Ccl dead after k_deform
    float* out = (float*)d_out;

    hipMemsetAsync(stats, 0, 512*sizeof(float), stream);
    k_wbf          <<<576,   256, 0, stream>>>(dcn_w, Wbf);
    k_updw256      <<<2048,  256, 0, stream>>>(x1, x2, dw_w, dw_b, Bo);
    k_pw           <<<1024,  256, 0, stream>>>(Bo, pw_w, pw_b, Ccl);
    k_offmask      <<<256,   256, 0, stream>>>(Ccl, p_w, p_b, m_w, m_b, OM);
    k_deform       <<<512,   256, 0, stream>>>(Ccl, OM, Wbf, D);
    k_stats_par    <<<1024,  256, 0, stream>>>(D, stats, 0);
    k_bngelu_dw128 <<<1024,  256, 0, stream>>>(D, stats, bn1g, bn1b, dw2w, dw2b, Hs);
    k_bn_relu_out  <<<16384, 256, 0, stream>>>(Hs, stats, bn2g, bn2b, out);
}

// Round 10
// 298.229 us; speedup vs baseline: 2.4450x; 1.2260x over previous
//
#include <hip/hip_runtime.h>
#include <math.h>

// Problem constants: B=8, spatial 64x64 (HW=4096), C_mid=256, C=128, N=9 taps.
// All inputs/outputs are float32.
typedef const float* fp;
typedef __attribute__((ext_vector_type(8))) short short8;   // 8 bf16 = 4 VGPRs (MFMA A/B frag)
typedef __attribute__((ext_vector_type(4))) float f32x4;    // MFMA C/D frag

__device__ __forceinline__ unsigned short f2bf(float f){    // RTNE float->bf16
    unsigned u = __float_as_uint(f);
    u += 0x7fff + ((u >> 16) & 1);
    return (unsigned short)(u >> 16);
}

// ---------------- K0a: dcn_w (o,c,9) -> Wbf[n][o][c] bf16
__global__ __launch_bounds__(256) void k_wbf(fp dcn_w, unsigned short* Wbf){
    int i = blockIdx.x*256 + threadIdx.x;       // 147456
    int c = i & 127, o = (i >> 7) & 127, n = i >> 14;
    Wbf[i] = f2bf(dcn_w[o*1152 + c*9 + n]);
}

// ---------------- K0b: p_w/m_w -> Wpm[n][32q][128c] bf16 (q>=27 zero)
__global__ __launch_bounds__(256) void k_wpm(fp pw, fp mw, unsigned short* Wpm){
    int i = blockIdx.x*256 + threadIdx.x;       // 36864 = 9*32*128
    int c = i & 127, q = (i >> 7) & 31, n = i >> 12;
    float v = 0.f;
    if(q < 18)      v = pw[q*1152 + c*9 + n];
    else if(q < 27) v = mw[(q-18)*1152 + c*9 + n];
    Wpm[i] = f2bf(v);
}

// ---------------- K1: fused upsample+concat+depthwise256 -> Bo (8,256,64,64)
__global__ __launch_bounds__(256) void k_updw256(fp x1, fp x2, fp w, fp bias, float* Bo){
    __shared__ float sA[66*68];
    int bid = blockIdx.x;
    int c = bid & 255, b = bid >> 8;
    int tid = threadIdx.x;
    for(int j = tid; j < 4356; j += 256){
        int r = j / 66, cpos = j - r*66;
        int yy = r - 1, xx = cpos - 1;
        float val = 0.f;
        if(yy >= 0 && yy < 64 && xx >= 0 && xx < 64){
            if(c < 128){
                val = x2[((b*128+c)<<12) + (yy<<6) + xx];
            } else {
                int cc = c - 128;
                const float s = 31.0f/63.0f;
                float fy = yy*s, fx = xx*s;
                int iy = (int)fy; if (iy > 30) iy = 30;
                int ix = (int)fx; if (ix > 30) ix = 30;
                float ty = fy - (float)iy, tx = fx - (float)ix;
                fp src = x1 + ((b*128+cc)<<10);
                float v00 = src[iy*32+ix],     v01 = src[iy*32+ix+1];
                float v10 = src[(iy+1)*32+ix], v11 = src[(iy+1)*32+ix+1];
                val = (v00*(1.f-ty)+v10*ty)*(1.f-tx) + (v01*(1.f-ty)+v11*ty)*tx;
            }
        }
        sA[r*68 + cpos] = val;
    }
    __syncthreads();
    float w0=w[c*9+0], w1=w[c*9+1], w2=w[c*9+2];
    float w3=w[c*9+3], w4=w[c*9+4], w5=w[c*9+5];
    float w6=w[c*9+6], w7=w[c*9+7], w8=w[c*9+8];
    float bv = bias[c];
    float* dst = Bo + ((size_t)(b*256+c)<<12);
    for(int j = tid; j < 4096; j += 256){
        int y = j >> 6, x = j & 63;
        const float* r0 = &sA[y*68 + x];
        float acc = bv
            + w0*r0[0]   + w1*r0[1]   + w2*r0[2]
            + w3*r0[68]  + w4*r0[69]  + w5*r0[70]
            + w6*r0[136] + w7*r0[137] + w8*r0[138];
        dst[j] = acc;
    }
}

// ---------------- K3: pointwise 256->128 + bias -> Ccl (channel-last only)
__global__ __launch_bounds__(256) void k_pw(const float* Bi, fp w, fp bias, float* Ccl){
    __shared__ float sIn[256*32];
    int bid = blockIdx.x;                       // 1024
    int b = bid >> 7;
    int pix0 = (bid & 127) << 5;
    int tid = threadIdx.x;
    for(int j = tid; j < 256*32; j += 256){
        int c = j >> 5, p = j & 31;
        sIn[j] = Bi[((b*256 + c)<<12) + pix0 + p];
    }
    __syncthreads();
    int og = tid >> 3, pg = tid & 7;
    int o0 = og*4, p0 = pg*4;
    float acc[4][4];
    #pragma unroll
    for(int i=0;i<4;i++){ float bv=bias[o0+i];
        #pragma unroll
        for(int j=0;j<4;j++) acc[i][j]=bv; }
    for(int c=0;c<256;c++){
        float4 xv = *(const float4*)&sIn[(c<<5)+p0];
        float w0=w[(o0+0)*256+c], w1=w[(o0+1)*256+c];
        float w2=w[(o0+2)*256+c], w3=w[(o0+3)*256+c];
        acc[0][0]+=w0*xv.x; acc[0][1]+=w0*xv.y; acc[0][2]+=w0*xv.z; acc[0][3]+=w0*xv.w;
        acc[1][0]+=w1*xv.x; acc[1][1]+=w1*xv.y; acc[1][2]+=w1*xv.z; acc[1][3]+=w1*xv.w;
        acc[2][0]+=w2*xv.x; acc[2][1]+=w2*xv.y; acc[2][2]+=w2*xv.z; acc[2][3]+=w2*xv.w;
        acc[3][0]+=w3*xv.x; acc[3][1]+=w3*xv.y; acc[3][2]+=w3*xv.z; acc[3][3]+=w3*xv.w;
    }
    #pragma unroll
    for(int j=0;j<4;j++){
        int px = pix0 + p0 + j;
        *(float4*)&Ccl[((size_t)(b<<12) + px)*128 + o0] =
            make_float4(acc[0][j],acc[1][j],acc[2][j],acc[3][j]);
    }
}

// ---------------- K4: offset(18)+mask(9, sigmoid) 3x3 conv via bf16 MFMA -> OM (8,27,4096)
// Grid 512 = 64 rows x 8 b (b = blockIdx&7, XCD affinity). Block: 32q x 64px (one row),
// K=1152 as 9 taps x 128c. Per tap: shifted-row stage of Ccl -> sX bf16 + Wpm tile -> sW;
// wave = 32q x 16px -> 2 frags; 8 MFMA/wave/tap. Runtime probe resolves C/D orientation.
__global__ __launch_bounds__(256) void k_offmask(fp Ccl, const unsigned short* Wpm,
                                                 fp pb, fp mb, float* OM){
    __shared__ __align__(16) unsigned short sW[32*136];   // [q][c] bf16
    __shared__ __align__(16) unsigned short sX[64*136];   // [px][c] bf16
    int b = blockIdx.x & 7;
    int y = blockIdx.x >> 3;          // output row
    int pix0 = y << 6;
    int tid = threadIdx.x;
    int lane = tid & 63, wave = tid >> 6;
    int m16 = lane & 15, quad = lane >> 4;
    int wp = wave << 4;               // px-subtile
    const float* cb = Ccl + (size_t)(b<<12)*128;

    // ---- probe (same as k_deform): D[m][n]=m*(n+100)
    short8 ap = {0,0,0,0,0,0,0,0}, bpr = {0,0,0,0,0,0,0,0};
    if(quad == 0){
        ap[0]  = (short)f2bf((float)m16);
        bpr[0] = (short)f2bf((float)(m16+100));
    }
    f32x4 dp = {0.f,0.f,0.f,0.f};
    dp = __builtin_amdgcn_mfma_f32_16x16x32_bf16(ap, bpr, dp, 0,0,0);
    bool p1 = true;
    #pragma unroll
    for(int r=0;r<4;r++){
        float expP1 = (float)(quad*4+r) * (float)(m16+100);
        p1 = p1 && (fabsf(dp[r]-expP1) < 0.5f);
    }
    bool swapD = (__ballot(p1) != 0xFFFFFFFFFFFFFFFFull);

    f32x4 acc[2];
    acc[0] = (f32x4){0.f,0.f,0.f,0.f};
    acc[1] = (f32x4){0.f,0.f,0.f,0.f};

    for(int n=0;n<9;n++){
        int ky = n/3, kx = n - ky*3;
        int yy = y + ky - 1;
        bool rowok = (yy>=0 && yy<64);
        // stage weights: 512 int4 = 32q x 128c bf16
        const int4* wsrc = (const int4*)(Wpm + (n<<12));
        for(int j=tid; j<512; j+=256){
            int q = j >> 4, cg = j & 15;
            *(int4*)&sW[q*136 + (cg<<3)] = wsrc[j];
        }
        // stage X: shifted row read, cg fastest (coalesced + conflict-free b64 writes)
        #pragma unroll
        for(int it=0; it<8; it++){
            int e = tid + (it<<8);
            int cg = (e & 31) << 2, px = e >> 5;
            int xx = px + kx - 1;
            float4 v = make_float4(0.f,0.f,0.f,0.f);
            if(rowok && xx>=0 && xx<64)
                v = *(const float4*)&cb[(size_t)((yy<<6)+xx)*128 + cg];
            unsigned long long pk = (unsigned long long)f2bf(v.x)
                | ((unsigned long long)f2bf(v.y)<<16)
                | ((unsigned long long)f2bf(v.z)<<32)
                | ((unsigned long long)f2bf(v.w)<<48);
            *(unsigned long long*)&sX[px*136 + cg] = pk;
        }
        __syncthreads();
        #pragma unroll
        for(int ks=0; ks<4; ks++){
            int k0 = ks << 5;
            short8 bfr = *(const short8*)&sX[(wp + m16)*136 + k0 + (quad<<3)];
            #pragma unroll
            for(int qt=0;qt<2;qt++){
                short8 afr = *(const short8*)&sW[((qt<<4) + m16)*136 + k0 + (quad<<3)];
                acc[qt] = __builtin_amdgcn_mfma_f32_16x16x32_bf16(afr, bfr, acc[qt], 0,0,0);
            }
        }
        __syncthreads();                 // MFMA reads done before next tap's overwrite
    }
    // epilogue: bias + sigmoid(mask), orientation per probe
    if(!swapD){
        #pragma unroll
        for(int qt=0;qt<2;qt++){
            int px = pix0 + wp + m16;
            #pragma unroll
            for(int r=0;r<4;r++){
                int q = (qt<<4) + (quad<<2) + r;
                if(q < 27){
                    float v = acc[qt][r] + ((q<18) ? pb[q] : mb[q-18]);
                    if(q>=18) v = 1.f/(1.f+expf(-v));
                    OM[((b*27+q)<<12) + px] = v;
                }
            }
        }
    } else {
        #pragma unroll
        for(int qt=0;qt<2;qt++){
            int q = (qt<<4) + m16;
            if(q < 27){
                float bias = (q<18) ? pb[q] : mb[q-18];
                #pragma unroll
                for(int r=0;r<4;r++){
                    int px = pix0 + wp + (quad<<2) + r;
                    float v = acc[qt][r] + bias;
                    if(q>=18) v = 1.f/(1.f+expf(-v));
                    OM[((b*27+q)<<12) + px] = v;
                }
            }
        }
    }
}

// ---------------- K5: deformable sampling + bf16 MFMA combine, 64-px tiles.
__global__ __launch_bounds__(256) void k_deform(fp Ccl, fp OM, const unsigned short* Wbf, float* D){
    __shared__ __align__(16) unsigned short sW[128*136];  // [o][c] bf16, 272B rows
    __shared__ __align__(16) unsigned short sX[64*136];   // [px][c] bf16
    __shared__ int   sBase[9*64*4];                        // [n][px][corner]
    __shared__ float sGw[9*64*4];
    int b = blockIdx.x & 7;
    int pix0 = (blockIdx.x >> 3) << 6;
    int tid = threadIdx.x;
    int lane = tid & 63, wave = tid >> 6;
    int m16 = lane & 15, quad = lane >> 4;
    int wo = (wave & 1) << 6;       // o-half: 0/64
    int wp = (wave >> 1) << 5;      // px-half: 0/32
    const float* omb = OM + b*27*4096;
    const float* cb  = Ccl + (size_t)(b<<12)*128;

    // ---- probe
    short8 ap = {0,0,0,0,0,0,0,0}, bpr = {0,0,0,0,0,0,0,0};
    if(quad == 0){
        ap[0]  = (short)f2bf((float)m16);
        bpr[0] = (short)f2bf((float)(m16+100));
    }
    f32x4 dp = {0.f,0.f,0.f,0.f};
    dp = __builtin_amdgcn_mfma_f32_16x16x32_bf16(ap, bpr, dp, 0,0,0);
    bool p1 = true;
    #pragma unroll
    for(int r=0;r<4;r++){
        float expP1 = (float)(quad*4+r) * (float)(m16+100);
        p1 = p1 && (fabsf(dp[r]-expP1) < 0.5f);
    }
    bool swapD = (__ballot(p1) != 0xFFFFFFFFFFFFFFFFull);

    f32x4 acc[4][2];
    #pragma unroll
    for(int i=0;i<4;i++){
        #pragma unroll
        for(int j=0;j<2;j++) acc[i][j] = (f32x4){0.f,0.f,0.f,0.f};
    }

    // ---- meta for all 9 taps (576 = 9 n x 64 px)
    for(int i = tid; i < 576; i += 256){
        int n = i >> 6, t = i & 63;
        int pix = pix0 + t, y = pix>>6, x = pix&63;
        float offx = omb[(n<<12)+pix];
        float offy = omb[((n+9)<<12)+pix];
        float m    = omb[((n+18)<<12)+pix];
        float pxf = (float)(y + n/3) + offx;
        float pyf = (float)(x + n%3) + offy;
        float fx = floorf(pxf), fy = floorf(pyf);
        float qx0 = fminf(fmaxf(fx,0.f),65.f), qx1 = fminf(fmaxf(fx+1.f,0.f),65.f);
        float qy0 = fminf(fmaxf(fy,0.f),65.f), qy1 = fminf(fmaxf(fy+1.f,0.f),65.f);
        float pxc = fminf(fmaxf(pxf,0.f),65.f), pyc = fminf(fmaxf(pyf,0.f),65.f);
        float glt = (1.f+(qx0-pxc))*(1.f+(qy0-pyc))*m;
        float grb = (1.f-(qx1-pxc))*(1.f-(qy1-pyc))*m;
        float glb = (1.f+(qx0-pxc))*(1.f-(qy1-pyc))*m;
        float grt = (1.f-(qx1-pxc))*(1.f+(qy0-pyc))*m;
        int ax0=(int)qx0, ax1=(int)qx1, ay0=(int)qy0, ay1=(int)qy1;
        int base = i << 2;
        sBase[base+0] = (ax0>=1&&ax0<=64&&ay0>=1&&ay0<=64) ? (((ax0-1)<<6)+(ay0-1)) : -1;
        sBase[base+1] = (ax1>=1&&ax1<=64&&ay1>=1&&ay1<=64) ? (((ax1-1)<<6)+(ay1-1)) : -1;
        sBase[base+2] = (ax0>=1&&ax0<=64&&ay1>=1&&ay1<=64) ? (((ax0-1)<<6)+(ay1-1)) : -1;
        sBase[base+3] = (ax1>=1&&ax1<=64&&ay0>=1&&ay0<=64) ? (((ax1-1)<<6)+(ay0-1)) : -1;
        sGw[base+0]=glt; sGw[base+1]=grb; sGw[base+2]=glb; sGw[base+3]=grt;
    }
    __syncthreads();

    for(int n=0;n<9;n++){
        {
            const int4* src = (const int4*)(Wbf + (n<<14));
            for(int j = tid; j < 2048; j += 256){
                int o = j >> 4, cg = j & 15;
                *(int4*)&sW[o*136 + (cg<<3)] = src[(o<<4) + cg];
            }
        }
        #pragma unroll
        for(int it=0; it<8; it++){
            int e = tid + (it<<8);
            int cg = (e & 31) << 2, px = e >> 5;
            int mb4 = ((n<<6) + px) << 2;
            const int* bp = &sBase[mb4];
            const float* gp = &sGw[mb4];
            float4 v = make_float4(0.f,0.f,0.f,0.f);
            #pragma unroll
            for(int k=0;k<4;k++){
                int bs = bp[k];
                if(bs>=0){
                    float g = gp[k];
                    float4 r = *(const float4*)&cb[(bs<<7) + cg];
                    v.x += g*r.x; v.y += g*r.y; v.z += g*r.z; v.w += g*r.w;
                }
            }
            unsigned long long pk = (unsigned long long)f2bf(v.x)
                | ((unsigned long long)f2bf(v.y)<<16)
                | ((unsigned long long)f2bf(v.z)<<32)
                | ((unsigned long long)f2bf(v.w)<<48);
            *(unsigned long long*)&sX[px*136 + cg] = pk;
        }
        __syncthreads();
        #pragma unroll
        for(int ks=0; ks<4; ks++){
            int k0 = ks << 5;
            short8 bfr[2];
            #pragma unroll
            for(int pt=0;pt<2;pt++)
                bfr[pt] = *(const short8*)&sX[(wp + (pt<<4) + m16)*136 + k0 + (quad<<3)];
            #pragma unroll
            for(int ot=0;ot<4;ot++){
                short8 afr = *(const short8*)&sW[(wo + (ot<<4) + m16)*136 + k0 + (quad<<3)];
                #pragma unroll
                for(int pt=0;pt<2;pt++)
                    acc[ot][pt] = __builtin_amdgcn_mfma_f32_16x16x32_bf16(afr, bfr[pt], acc[ot][pt], 0,0,0);
            }
        }
        __syncthreads();
    }
    if(!swapD){
        #pragma unroll
        for(int ot=0;ot<4;ot++){
            #pragma unroll
            for(int pt=0;pt<2;pt++){
                int px = pix0 + wp + (pt<<4) + m16;
                #pragma unroll
                for(int r=0;r<4;r++){
                    int o = wo + (ot<<4) + (quad<<2) + r;
                    D[((b*128+o)<<12) + px] = acc[ot][pt][r];
                }
            }
        }
    } else {
        #pragma unroll
        for(int ot=0;ot<4;ot++){
            #pragma unroll
            for(int pt=0;pt<2;pt++){
                int o = wo + (ot<<4) + m16;
                #pragma unroll
                for(int r=0;r<4;r++){
                    int px = pix0 + wp + (pt<<4) + (quad<<2) + r;
                    D[((b*128+o)<<12) + px] = acc[ot][pt][r];
                }
            }
        }
    }
}

// ---------------- stats (parallel, atomic raw sums)
__global__ __launch_bounds__(256) void k_stats_par(const float* src, float* stats, int statOfs){
    __shared__ float sd[256], sq[256];
    int bid = blockIdx.x;                // 1024 = 8 b x 128 c
    int c = bid & 127, b = bid >> 7;
    int tid = threadIdx.x;
    const float* p = src + ((size_t)(b*128+c)<<12);
    float s = 0.f, s2 = 0.f;
    for(int i=tid; i<4096; i+=256){ float v = p[i]; s += v; s2 += v*v; }
    sd[tid]=s; sq[tid]=s2; __syncthreads();
    for(int off=128; off>0; off>>=1){
        if(tid<off){ sd[tid]+=sd[tid+off]; sq[tid]+=sq[tid+off]; }
        __syncthreads();
    }
    if(tid==0){
        atomicAdd(&stats[statOfs+c], sd[0]);
        atomicAdd(&stats[statOfs+128+c], sq[0]);
    }
}

// ---------------- K7: fused BN1+GELU + depthwise128 -> Hs, + atomic stats2 partials
__global__ __launch_bounds__(256) void k_bngelu_dw128(const float* Dsrc, float* stats,
                                                      fp g1, fp b1, fp w, fp bias, float* Hs){
    __shared__ float sG[66*68];
    __shared__ float sd[256], sq[256];
    int bid = blockIdx.x;
    int c = bid & 127, b = bid >> 7;
    int tid = threadIdx.x;
    float mean1 = stats[c] * (1.f/32768.f);
    float var1  = stats[128+c] * (1.f/32768.f) - mean1*mean1;
    float rstd1 = rsqrtf(var1 + 1e-5f);
    float sc = rstd1 * g1[c];
    float sb = b1[c] - mean1*sc;
    const float* dplane = Dsrc + ((size_t)(b*128+c)<<12);
    for(int j = tid; j < 4356; j += 256){
        int r = j / 66, cpos = j - r*66;
        int yy = r - 1, xx = cpos - 1;
        float val = 0.f;
        if(yy >= 0 && yy < 64 && xx >= 0 && xx < 64){
            float v = dplane[(yy<<6)+xx]*sc + sb;
            val = 0.5f*v*(1.0f + erff(v*0.70710678118654752f));
        }
        sG[r*68 + cpos] = val;
    }
    __syncthreads();
    float w0=w[c*9+0], w1=w[c*9+1], w2=w[c*9+2];
    float w3=w[c*9+3], w4=w[c*9+4], w5=w[c*9+5];
    float w6=w[c*9+6], w7=w[c*9+7], w8=w[c*9+8];
    float bv = bias[c];
    float* dst = Hs + ((size_t)(b*128+c)<<12);
    float s = 0.f, s2 = 0.f;
    for(int j = tid; j < 4096; j += 256){
        int y = j >> 6, x = j & 63;
        const float* r0 = &sG[y*68 + x];
        float acc = bv
            + w0*r0[0]   + w1*r0[1]   + w2*r0[2]
            + w3*r0[68]  + w4*r0[69]  + w5*r0[70]
            + w6*r0[136] + w7*r0[137] + w8*r0[138];
        dst[j] = acc;
        s += acc; s2 += acc*acc;
    }
    sd[tid]=s; sq[tid]=s2; __syncthreads();
    for(int off=128; off>0; off>>=1){
        if(tid<off){ sd[tid]+=sd[tid+off]; sq[tid]+=sq[tid+off]; }
        __syncthreads();
    }
    if(tid==0){
        atomicAdd(&stats[256+c], sd[0]);
        atomicAdd(&stats[384+c], sq[0]);
    }
}

// ---------------- BN2 + ReLU -> f32 out (finalizes stats2 sums inline)
__global__ __launch_bounds__(256) void k_bn_relu_out(const float* Hs, const float* stats, fp g, fp bb, float* out){
    int idx = blockIdx.x*256+threadIdx.x;       // 4,194,304
    int c = (idx>>12)&127;
    float mean2 = stats[256+c] * (1.f/32768.f);
    float var2  = stats[384+c] * (1.f/32768.f) - mean2*mean2;
    float rstd2 = rsqrtf(var2 + 1e-5f);
    float v = (Hs[idx]-mean2)*rstd2*g[c] + bb[c];
    out[idx] = fmaxf(v,0.f);
}

extern "C" void kernel_launch(void* const* d_in, const int* in_sizes, int n_in,
                              void* d_out, int out_size, void* d_ws, size_t ws_size,
                              hipStream_t stream){
    fp x1   = (fp)d_in[0];
    fp x2   = (fp)d_in[1];
    fp dw_w = (fp)d_in[2];  fp dw_b = (fp)d_in[3];
    fp pw_w = (fp)d_in[4];  fp pw_b = (fp)d_in[5];
    fp p_w  = (fp)d_in[6];  fp p_b  = (fp)d_in[7];
    fp m_w  = (fp)d_in[8];  fp m_b  = (fp)d_in[9];
    fp dcn_w= (fp)d_in[10];
    fp bn1g = (fp)d_in[11]; fp bn1b = (fp)d_in[12];
    fp dw2w = (fp)d_in[13]; fp dw2b = (fp)d_in[14];
    fp bn2g = (fp)d_in[15]; fp bn2b = (fp)d_in[16];

    float* ws  = (float*)d_ws;
    float* Bo  = ws;                    // (8,256,4096) = 8,388,608 f ; D reuses after k_pw
    float* Ccl = ws + 8388608;          // (8,4096,128) = 4,194,304 f ; Hs reuses after k_deform
    float* OM  = ws + 12582912;         // (8,27,4096)  =   884,736 f
    unsigned short* Wbf = (unsigned short*)(ws + 13467648);  // 147,456 bf16 (73,728 f)
    unsigned short* Wpm = (unsigned short*)(ws + 13541376);  //  36,864 bf16 (18,432 f)
    float* stats = ws + 13559808;       // 512 f (sum1, sq1, sum2, sq2)
    float* D   = Bo;                    // Bo dead after k_pw
    float* Hs  = Ccl;                   // Ccl dead after k_deform
    float* out = (float*)d_out;

    hipMemsetAsync(stats, 0, 512*sizeof(float), stream);
    k_wbf          <<<576,   256, 0, stream>>>(dcn_w, Wbf);
    k_wpm          <<<144,   256, 0, stream>>>(p_w, m_w, Wpm);
    k_updw256      <<<2048,  256, 0, stream>>>(x1, x2, dw_w, dw_b, Bo);
    k_pw           <<<1024,  256, 0, stream>>>(Bo, pw_w, pw_b, Ccl);
    k_offmask      <<<512,   256, 0, stream>>>(Ccl, Wpm, p_b, m_b, OM);
    k_deform       <<<512,   256, 0, stream>>>(Ccl, OM, Wbf, D);
    k_stats_par    <<<1024,  256, 0, stream>>>(D, stats, 0);
    k_bngelu_dw128 <<<1024,  256, 0, stream>>>(D, stats, bn1g, bn1b, dw2w, dw2b, Hs);
    k_bn_relu_out  <<<16384, 256, 0, stream>>>(Hs, stats, bn2g, bn2b, out);
}